// Round 4
// baseline (34.940 us; speedup 1.0000x reference)
//
#include <hip/hip_runtime.h>
#include <cmath>

#ifndef M_PI
#define M_PI 3.14159265358979323846
#endif

namespace {

constexpr int VDIM = 512;
constexpr int RDIM = 1024;
constexpr int TX = 256;          // pixels per block (one output row)
constexpr int COLS = TX + 12;    // staged columns (268)

struct Net {
  int cnt;
  int a[96];
  int b[96];
};

// Batcher odd-even mergesort (arbitrary n), descending.
constexpr Net make_batcher(int n) {
  Net net{};
  net.cnt = 0;
  for (int p = 1; p < n; p *= 2)
    for (int k = p; k >= 1; k /= 2)
      for (int j = k % p; j + k < n; j += 2 * k)
        for (int i = 0; i < k && i + j + k < n; ++i)
          if ((i + j) / (2 * p) == (i + j + k) / (2 * p)) {
            net.a[net.cnt] = i + j;
            net.b[net.cnt] = i + j + k;
            ++net.cnt;
          }
  return net;
}

// Descending sorter for a BITONIC input of length n (front-pad +inf elided).
constexpr Net make_bitonic_desc(int n) {
  int P = 1;
  while (P < n) P *= 2;
  int F = P - n;
  Net net{};
  net.cnt = 0;
  for (int d = P / 2; d >= 1; d /= 2)
    for (int i = F; i + d < P; ++i)
      if ((i & d) == 0) {
        net.a[net.cnt] = i - F;
        net.b[net.cnt] = i - F + d;
        ++net.cnt;
      }
  return net;
}

constexpr Net NET8 = make_batcher(8);
constexpr Net NET5 = make_batcher(5);
constexpr Net B13 = make_bitonic_desc(13);
constexpr Net B16 = make_bitonic_desc(16);
constexpr Net B26 = make_bitonic_desc(26);
constexpr Net B32 = make_bitonic_desc(32);
constexpr Net B36 = make_bitonic_desc(36);

// ---- LDS layout (float offsets); SF and GP alias (SF dead before GP built)
constexpr int SP_W = 28;  // sorted-26 pair, padded to 28 dwords (16B-aligned)
constexpr int SG_W = 12;  // sorted-8 gap col, padded
constexpr int UF_W = 20;  // sorted-13 col / sorted-16 gap pair, padded
constexpr int SP_OFF = 0;
constexpr int SG_OFF = SP_OFF + 267 * SP_W;   // 7476
constexpr int UF_OFF = SG_OFF + COLS * SG_W;  // 10692
constexpr int SMEM_F = UF_OFF + COLS * UF_W;  // 16052 floats = 64208 B

}  // namespace

__device__ __forceinline__ void cx_desc(float& x, float& y) {
  float mx = fmaxf(x, y);
  float mn = fminf(x, y);
  x = mx;
  y = mn;
}

#define DEF_APPLY(NAME, NET, L)                                      \
  __device__ __forceinline__ void NAME(float(&v)[L]) {               \
    _Pragma("unroll") for (int c = 0; c < NET.cnt; ++c)              \
        cx_desc(v[NET.a[c]], v[NET.b[c]]);                           \
  }

DEF_APPLY(net8, NET8, 8)
DEF_APPLY(net5, NET5, 5)
DEF_APPLY(b13, B13, 13)
DEF_APPLY(b16, B16, 16)
DEF_APPLY(b26, B26, 26)
DEF_APPLY(b32, B32, 32)
DEF_APPLY(b36, B36, 36)

__device__ __forceinline__ void ld4(float* d, const float* p, int nvec) {
#pragma unroll
  for (int j = 0; j < 4; ++j)
    if (j < nvec) *(float4*)(d + 4 * j) = *(const float4*)(p + 4 * j);
}

// top-36 of two descending sorted-26 lists (padded to 28; idx 26,27 unused)
__device__ __forceinline__ void cap36_2626(float (&S)[36], const float (&x)[28],
                                           const float (&y)[28]) {
#pragma unroll
  for (int i = 0; i < 10; ++i) S[i] = x[i];
#pragma unroll
  for (int i = 10; i < 26; ++i) S[i] = fmaxf(x[i], y[35 - i]);
#pragma unroll
  for (int i = 26; i < 36; ++i) S[i] = y[35 - i];
}

__global__ __launch_bounds__(256, 2) void cfar_os_kernel(const float* __restrict__ in,
                                                         float* __restrict__ out,
                                                         float alpha) {
  __shared__ float smem[SMEM_F];
  float* SP = smem + SP_OFF;  // [267][28] sorted-26 column pairs
  float* SG = smem + SG_OFF;  // [268][12] sorted-8 gap columns
  float* SF = smem + UF_OFF;  // [268][20] sorted-13 full columns (stage 1-2)
  float* GP = smem + UF_OFF;  // [267][20] sorted-16 gap pairs (stage 3+, alias)

  const int t = threadIdx.x;
  const int r0 = blockIdx.y;
  const int c0 = blockIdx.x * TX;

  // ---- stage 1: per-column sorts ----
  for (int cc = t; cc < COLS; cc += 256) {
    const int gc = (c0 + cc - 6) & (RDIM - 1);
    float v[13];
#pragma unroll
    for (int dy = 0; dy < 13; ++dy)
      v[dy] = in[(((r0 + dy - 6) & (VDIM - 1)) << 10) + gc];
    float g[8] = {v[0], v[1], v[2], v[3], v[9], v[10], v[11], v[12]};
    net8(g);
    float m[5] = {v[4], v[5], v[6], v[7], v[8]};
    net5(m);
    float f[13];
#pragma unroll
    for (int p = 0; p < 8; ++p) f[p] = g[p];
    f[8] = m[4]; f[9] = m[3]; f[10] = m[2]; f[11] = m[1]; f[12] = m[0];
    b13(f);
    float4* df = (float4*)(SF + cc * UF_W);
    df[0] = make_float4(f[0], f[1], f[2], f[3]);
    df[1] = make_float4(f[4], f[5], f[6], f[7]);
    df[2] = make_float4(f[8], f[9], f[10], f[11]);
    df[3] = make_float4(f[12], -INFINITY, -INFINITY, -INFINITY);
    float4* dg = (float4*)(SG + cc * SG_W);
    dg[0] = make_float4(g[0], g[1], g[2], g[3]);
    dg[1] = make_float4(g[4], g[5], g[6], g[7]);
  }
  __syncthreads();

  // ---- stage 2: sorted-26 pairs from adjacent sorted-13 columns ----
  for (int cc = t; cc < COLS - 1; cc += 256) {
    float x[16], y[16];
    ld4(x, SF + cc * UF_W, 4);
    ld4(y, SF + (cc + 1) * UF_W, 4);
    float v[26];
#pragma unroll
    for (int j = 0; j < 13; ++j) v[j] = x[j];
#pragma unroll
    for (int j = 0; j < 13; ++j) v[13 + j] = y[12 - j];
    b26(v);
    float4* d = (float4*)(SP + cc * SP_W);
#pragma unroll
    for (int j = 0; j < 6; ++j) d[j] = make_float4(v[4 * j], v[4 * j + 1], v[4 * j + 2], v[4 * j + 3]);
    d[6] = make_float4(v[24], v[25], -INFINITY, -INFINITY);
  }
  __syncthreads();

  // ---- stage 3: sorted-16 gap pairs (overwrites SF region) ----
  for (int cc = t; cc < COLS - 1; cc += 256) {
    float x[8], y[8];
    ld4(x, SG + cc * SG_W, 2);
    ld4(y, SG + (cc + 1) * SG_W, 2);
    float v[16];
#pragma unroll
    for (int j = 0; j < 8; ++j) v[j] = x[j];
#pragma unroll
    for (int j = 0; j < 8; ++j) v[8 + j] = y[7 - j];
    b16(v);
    float4* d = (float4*)(GP + cc * UF_W);
#pragma unroll
    for (int j = 0; j < 4; ++j) d[j] = make_float4(v[4 * j], v[4 * j + 1], v[4 * j + 2], v[4 * j + 3]);
  }
  __syncthreads();

  // ---- per-pixel phase ----
  float x[28], y[28];

  // A-side: full cols t..t+3
  ld4(x, SP + (t + 0) * SP_W, 4); ld4(x + 16, SP + (t + 0) * SP_W + 16, 3);
  ld4(y, SP + (t + 2) * SP_W, 4); ld4(y + 16, SP + (t + 2) * SP_W + 16, 3);
  float A[36];
  cap36_2626(A, x, y);
  b36(A);

  // B-side full cols t+9..t+12
  ld4(x, SP + (t + 9) * SP_W, 4);  ld4(x + 16, SP + (t + 9) * SP_W + 16, 3);
  ld4(y, SP + (t + 11) * SP_W, 4); ld4(y + 16, SP + (t + 11) * SP_W + 16, 3);
  float B[36];
  cap36_2626(B, x, y);
  b36(B);

  // gap cols t+4..t+7 via two sorted-16 pairs
  float g1[16], g2[16];
  ld4(g1, GP + (t + 4) * UF_W, 4);
  ld4(g2, GP + (t + 6) * UF_W, 4);
  float G[32];
#pragma unroll
  for (int j = 0; j < 16; ++j) G[j] = g1[j];
#pragma unroll
  for (int j = 0; j < 16; ++j) G[16 + j] = g2[15 - j];
  b32(G);
#pragma unroll
  for (int i = 4; i < 36; ++i) B[i] = fmaxf(B[i], G[35 - i]);
  b36(B);

  // last gap col t+8 (sorted-8)
  float s8[8];
  ld4(s8, SG + (t + 8) * SG_W, 2);
#pragma unroll
  for (int i = 28; i < 36; ++i) B[i] = fmaxf(B[i], s8[35 - i]);
  b36(B);

  // ---- final: 36th largest of union = min_i max(A_i, B_{35-i}) ----
  float mm[36];
#pragma unroll
  for (int i = 0; i < 36; ++i) mm[i] = fmaxf(A[i], B[35 - i]);
#pragma unroll
  for (int i = 0; i < 18; ++i) mm[i] = fminf(mm[i], mm[i + 18]);
#pragma unroll
  for (int i = 0; i < 9; ++i) mm[i] = fminf(mm[i], mm[i + 9]);
#pragma unroll
  for (int i = 0; i < 4; ++i) mm[i] = fminf(mm[i], mm[i + 4]);
  mm[0] = fminf(mm[0], mm[8]);
  mm[0] = fminf(mm[0], fminf(mm[1], fminf(mm[2], mm[3])));

  out[(r0 << 10) + c0 + t] = alpha * mm[0];
}

// ---- host-side faithful port of the reference ALPHA computation ----
static double log_factorial_port(int n_) {
  double n = n_ + 1.0;
  if (n < 9.0) {
    double f = 1.0;
    for (int i = 2; i <= (int)(n + 0.5); ++i) f *= (double)i;
    return log(f);
  }
  return 0.5 * (log(2.0 * M_PI) - log(n)) +
         n * (log(n + 1.0 / (12.0 * n - 1.0 / (10.0 * n))) - 1.0);
}

static double cfar_fun(int k, int n, double t, double pfa) {
  double s = 0.0;
  for (int i = n; i > n - k; --i) s += log((double)i + t);
  return log_factorial_port(n) - log_factorial_port(n - k) - s - log(pfa);
}

static float compute_alpha() {
  double lo = 1.0, hi = 1e32;
  for (int it = 0; it < 300; ++it) {
    double mid = 0.5 * (lo + hi);
    if (cfar_fun(108, 144, mid, 1e-5) > 0.0)
      lo = mid;
    else
      hi = mid;
  }
  return (float)(0.5 * (lo + hi));
}

static const float g_alpha = compute_alpha();

extern "C" void kernel_launch(void* const* d_in, const int* in_sizes, int n_in,
                              void* d_out, int out_size, void* d_ws, size_t ws_size,
                              hipStream_t stream) {
  const float* in = (const float*)d_in[0];
  float* out = (float*)d_out;
  dim3 block(TX, 1);
  dim3 grid(RDIM / TX, VDIM);
  hipLaunchKernelGGL(cfar_os_kernel, grid, block, 0, stream, in, out, g_alpha);
}

// Round 5
// 30.361 us; speedup vs baseline: 1.1509x; 1.1509x over previous
//
#include <hip/hip_runtime.h>
#include <cmath>

#ifndef M_PI
#define M_PI 3.14159265358979323846
#endif

namespace {

constexpr int VDIM = 512;
constexpr int RDIM = 1024;
constexpr int TX = 256;        // pixels per block (one output row)
constexpr int COLS = TX + 12;  // 268 columns incl. halo
constexpr int NPAIR = COLS - 1;  // 267 adjacent-column pairs

struct Net {
  int cnt;
  int a[96];
  int b[96];
};

// Batcher odd-even mergesort (arbitrary n), descending.
constexpr Net make_batcher(int n) {
  Net net{};
  net.cnt = 0;
  for (int p = 1; p < n; p *= 2)
    for (int k = p; k >= 1; k /= 2)
      for (int j = k % p; j + k < n; j += 2 * k)
        for (int i = 0; i < k && i + j + k < n; ++i)
          if ((i + j) / (2 * p) == (i + j + k) / (2 * p)) {
            net.a[net.cnt] = i + j;
            net.b[net.cnt] = i + j + k;
            ++net.cnt;
          }
  return net;
}

// Descending sorter for a BITONIC input of length n (front-pad +inf elided).
constexpr Net make_bitonic_desc(int n) {
  int P = 1;
  while (P < n) P *= 2;
  int F = P - n;
  Net net{};
  net.cnt = 0;
  for (int d = P / 2; d >= 1; d /= 2)
    for (int i = F; i + d < P; ++i)
      if ((i & d) == 0) {
        net.a[net.cnt] = i - F;
        net.b[net.cnt] = i - F + d;
        ++net.cnt;
      }
  return net;
}

constexpr Net NET8 = make_batcher(8);
constexpr Net NET5 = make_batcher(5);
constexpr Net B13 = make_bitonic_desc(13);
constexpr Net B16 = make_bitonic_desc(16);
constexpr Net B26 = make_bitonic_desc(26);
constexpr Net B32 = make_bitonic_desc(32);
constexpr Net B36 = make_bitonic_desc(36);

}  // namespace

__device__ __forceinline__ void cx_desc(float& x, float& y) {
  float mx = fmaxf(x, y);
  float mn = fminf(x, y);
  x = mx;
  y = mn;
}

#define DEF_APPLY(NAME, NET, L)                                      \
  __device__ __forceinline__ void NAME(float(&v)[L]) {               \
    _Pragma("unroll") for (int c = 0; c < NET.cnt; ++c)              \
        cx_desc(v[NET.a[c]], v[NET.b[c]]);                           \
  }

DEF_APPLY(net8, NET8, 8)
DEF_APPLY(net5, NET5, 5)
DEF_APPLY(b13, B13, 13)
DEF_APPLY(b16, B16, 16)
DEF_APPLY(b26, B26, 26)
DEF_APPLY(b32, B32, 32)
DEF_APPLY(b36, B36, 36)

// sort a 13-cell column: f = sorted-13 desc, g = sorted gap-8 desc (byproduct)
__device__ __forceinline__ void sort_col13(const float (&v)[13], float (&f)[13],
                                           float (&g)[8]) {
  g[0] = v[0]; g[1] = v[1]; g[2] = v[2]; g[3] = v[3];
  g[4] = v[9]; g[5] = v[10]; g[6] = v[11]; g[7] = v[12];
  net8(g);
  float m[5] = {v[4], v[5], v[6], v[7], v[8]};
  net5(m);
#pragma unroll
  for (int p = 0; p < 8; ++p) f[p] = g[p];
  f[8] = m[4]; f[9] = m[3]; f[10] = m[2]; f[11] = m[1]; f[12] = m[0];
  b13(f);
}

__device__ __forceinline__ void load_pair(const float4* __restrict__ SP4, int c,
                                          float (&d)[28]) {
#pragma unroll
  for (int j = 0; j < 7; ++j) {
    float4 q = SP4[j * NPAIR + c];
    d[4 * j + 0] = q.x; d[4 * j + 1] = q.y; d[4 * j + 2] = q.z; d[4 * j + 3] = q.w;
  }
}

__device__ __forceinline__ void load_g8(const float4* __restrict__ SG4, int c,
                                        float (&d)[8]) {
  float4 a = SG4[c];
  float4 b = SG4[COLS + c];
  d[0] = a.x; d[1] = a.y; d[2] = a.z; d[3] = a.w;
  d[4] = b.x; d[5] = b.y; d[6] = b.z; d[7] = b.w;
}

// top-36 multiset of two descending sorted-26 lists (-inf padded identity)
__device__ __forceinline__ void cap36_2626(float (&S)[36], const float (&x)[28],
                                           const float (&y)[28]) {
#pragma unroll
  for (int i = 0; i < 10; ++i) S[i] = x[i];
#pragma unroll
  for (int i = 10; i < 26; ++i) S[i] = fmaxf(x[i], y[35 - i]);
#pragma unroll
  for (int i = 26; i < 36; ++i) S[i] = y[35 - i];
}

__global__ __launch_bounds__(256, 4) void cfar_os_kernel(const float* __restrict__ in,
                                                         float* __restrict__ out,
                                                         float alpha) {
  __shared__ float4 SP4[7 * NPAIR];  // sorted-26 pairs, chunked [7][267]
  __shared__ float4 SG4[2 * COLS];   // sorted gap-8 cols, chunked [2][268]

  const int t = threadIdx.x;
  const int r0 = blockIdx.y;
  const int c0 = blockIdx.x * TX;

  // ---- single cooperative stage: pair tasks straight from global ----
  for (int cc = t; cc < NPAIR; cc += 256) {
    const int gl = (c0 + cc - 6) & (RDIM - 1);
    const int gr = (c0 + cc - 5) & (RDIM - 1);
    float L[13], R[13];
#pragma unroll
    for (int dy = 0; dy < 13; ++dy) {
      const int rb = ((r0 + dy - 6) & (VDIM - 1)) << 10;
      L[dy] = in[rb + gl];
      R[dy] = in[rb + gr];
    }
    float lf[13], lg[8], rf[13], rg[8];
    sort_col13(L, lf, lg);
    sort_col13(R, rf, rg);
    float v[26];
#pragma unroll
    for (int j = 0; j < 13; ++j) v[j] = lf[j];
#pragma unroll
    for (int j = 0; j < 13; ++j) v[13 + j] = rf[12 - j];
    b26(v);
    SP4[0 * NPAIR + cc] = make_float4(v[0], v[1], v[2], v[3]);
    SP4[1 * NPAIR + cc] = make_float4(v[4], v[5], v[6], v[7]);
    SP4[2 * NPAIR + cc] = make_float4(v[8], v[9], v[10], v[11]);
    SP4[3 * NPAIR + cc] = make_float4(v[12], v[13], v[14], v[15]);
    SP4[4 * NPAIR + cc] = make_float4(v[16], v[17], v[18], v[19]);
    SP4[5 * NPAIR + cc] = make_float4(v[20], v[21], v[22], v[23]);
    SP4[6 * NPAIR + cc] = make_float4(v[24], v[25], -INFINITY, -INFINITY);
    SG4[cc] = make_float4(lg[0], lg[1], lg[2], lg[3]);
    SG4[COLS + cc] = make_float4(lg[4], lg[5], lg[6], lg[7]);
  }
  __syncthreads();

  // ---- per-pixel phase (B-side first to minimize register liveness) ----
  float B[36];
  {
    float x[28], y[28];
    load_pair(SP4, t + 9, x);
    load_pair(SP4, t + 11, y);
    cap36_2626(B, x, y);
  }
  b36(B);

  float G[32];
  {
    float a[8], b8[8];
    float g1[16], g2[16];
    load_g8(SG4, t + 4, a);
    load_g8(SG4, t + 5, b8);
#pragma unroll
    for (int j = 0; j < 8; ++j) { g1[j] = a[j]; g1[8 + j] = b8[7 - j]; }
    b16(g1);
    load_g8(SG4, t + 6, a);
    load_g8(SG4, t + 7, b8);
#pragma unroll
    for (int j = 0; j < 8; ++j) { g2[j] = a[j]; g2[8 + j] = b8[7 - j]; }
    b16(g2);
#pragma unroll
    for (int j = 0; j < 16; ++j) { G[j] = g1[j]; G[16 + j] = g2[15 - j]; }
  }
  b32(G);
#pragma unroll
  for (int i = 4; i < 36; ++i) B[i] = fmaxf(B[i], G[35 - i]);
  b36(B);
  {
    float s8[8];
    load_g8(SG4, t + 8, s8);
#pragma unroll
    for (int i = 28; i < 36; ++i) B[i] = fmaxf(B[i], s8[35 - i]);
  }
  b36(B);

  float A[36];
  {
    float x[28], y[28];
    load_pair(SP4, t + 0, x);
    load_pair(SP4, t + 2, y);
    cap36_2626(A, x, y);
  }
  b36(A);

  // ---- final: 36th largest of union = min_i max(A_i, B_{35-i}) ----
  float mm[36];
#pragma unroll
  for (int i = 0; i < 36; ++i) mm[i] = fmaxf(A[i], B[35 - i]);
#pragma unroll
  for (int i = 0; i < 18; ++i) mm[i] = fminf(mm[i], mm[i + 18]);
#pragma unroll
  for (int i = 0; i < 9; ++i) mm[i] = fminf(mm[i], mm[i + 9]);
#pragma unroll
  for (int i = 0; i < 4; ++i) mm[i] = fminf(mm[i], mm[i + 4]);
  mm[0] = fminf(mm[0], mm[8]);
  mm[0] = fminf(mm[0], fminf(mm[1], fminf(mm[2], mm[3])));

  out[(r0 << 10) + c0 + t] = alpha * mm[0];
}

// ---- host-side faithful port of the reference ALPHA computation ----
static double log_factorial_port(int n_) {
  double n = n_ + 1.0;
  if (n < 9.0) {
    double f = 1.0;
    for (int i = 2; i <= (int)(n + 0.5); ++i) f *= (double)i;
    return log(f);
  }
  return 0.5 * (log(2.0 * M_PI) - log(n)) +
         n * (log(n + 1.0 / (12.0 * n - 1.0 / (10.0 * n))) - 1.0);
}

static double cfar_fun(int k, int n, double t, double pfa) {
  double s = 0.0;
  for (int i = n; i > n - k; --i) s += log((double)i + t);
  return log_factorial_port(n) - log_factorial_port(n - k) - s - log(pfa);
}

static float compute_alpha() {
  double lo = 1.0, hi = 1e32;
  for (int it = 0; it < 300; ++it) {
    double mid = 0.5 * (lo + hi);
    if (cfar_fun(108, 144, mid, 1e-5) > 0.0)
      lo = mid;
    else
      hi = mid;
  }
  return (float)(0.5 * (lo + hi));
}

static const float g_alpha = compute_alpha();

extern "C" void kernel_launch(void* const* d_in, const int* in_sizes, int n_in,
                              void* d_out, int out_size, void* d_ws, size_t ws_size,
                              hipStream_t stream) {
  const float* in = (const float*)d_in[0];
  float* out = (float*)d_out;
  dim3 block(TX, 1);
  dim3 grid(RDIM / TX, VDIM);
  hipLaunchKernelGGL(cfar_os_kernel, grid, block, 0, stream, in, out, g_alpha);
}

// Round 6
// 23.563 us; speedup vs baseline: 1.4828x; 1.2885x over previous
//
#include <hip/hip_runtime.h>
#include <cmath>

#ifndef M_PI
#define M_PI 3.14159265358979323846
#endif

typedef _Float16 h2 __attribute__((ext_vector_type(2)));
typedef _Float16 h4 __attribute__((ext_vector_type(4)));
typedef _Float16 h8 __attribute__((ext_vector_type(8)));

#define NINF ((_Float16)-INFINITY)

namespace {

constexpr int VDIM = 512;
constexpr int RDIM = 1024;
constexpr int TX = 256;          // pixels per block (one output row)
constexpr int COLS = TX + 12;    // 268 cols incl. halo
constexpr int NPAIR = COLS - 1;  // 267 adjacent-col pairs

constexpr int SP_W = 28;  // halfs per pair row (56 B)
constexpr int SG_W = 8;   // halfs per gap row (16 B)

struct Net {
  int cnt;
  int a[96];
  int b[96];
};

// Batcher odd-even mergesort (arbitrary n), descending (max to low index).
constexpr Net make_batcher(int n) {
  Net net{};
  net.cnt = 0;
  for (int p = 1; p < n; p *= 2)
    for (int k = p; k >= 1; k /= 2)
      for (int j = k % p; j + k < n; j += 2 * k)
        for (int i = 0; i < k && i + j + k < n; ++i)
          if ((i + j) / (2 * p) == (i + j + k) / (2 * p)) {
            net.a[net.cnt] = i + j;
            net.b[net.cnt] = i + j + k;
            ++net.cnt;
          }
  return net;
}

// Descending sorter for a BITONIC input of length n (front +inf pads elided).
constexpr Net make_bitonic_desc(int n) {
  int P = 1;
  while (P < n) P *= 2;
  int F = P - n;
  Net net{};
  net.cnt = 0;
  for (int d = P / 2; d >= 1; d /= 2)
    for (int i = F; i + d < P; ++i)
      if ((i & d) == 0) {
        net.a[net.cnt] = i - F;
        net.b[net.cnt] = i - F + d;
        ++net.cnt;
      }
  return net;
}

// Packed (half2) bitonic sorter: d>=2 layers as full-reg pk ops (elements
// 2j,2j+1 live in reg j; even front-pad keeps siblings aligned), d=1 layer
// as in-register .x/.y scalar ops. Requires F = pow2pad - n even.
struct PkNet {
  int npk;
  int pa[48];
  int pb[48];
  int nsc;
  int sc[24];
};

constexpr PkNet make_pk(int n) {
  int P = 1;
  while (P < n) P *= 2;
  int F = P - n;  // even for n = 36, 32, 16
  PkNet t{};
  for (int d = P / 2; d >= 2; d /= 2)
    for (int vi = F; vi + d < P; vi += 2)
      if ((vi & d) == 0) {
        t.pa[t.npk] = (vi - F) / 2;
        t.pb[t.npk] = (vi - F + d) / 2;
        ++t.npk;
      }
  for (int vi = F; vi + 1 < P; vi += 2) t.sc[t.nsc++] = (vi - F) / 2;
  return t;
}

constexpr Net NET8 = make_batcher(8);
constexpr Net NET5 = make_batcher(5);
constexpr Net B13 = make_bitonic_desc(13);
constexpr Net B26S = make_bitonic_desc(26);
constexpr PkNet PK16 = make_pk(16);
constexpr PkNet PK32 = make_pk(32);
constexpr PkNet PK36 = make_pk(36);

}  // namespace

__device__ __forceinline__ h2 mk2(_Float16 a, _Float16 b) {
  h2 v;
  v.x = a;
  v.y = b;
  return v;
}
__device__ __forceinline__ h2 pmax(h2 a, h2 b) { return __builtin_elementwise_max(a, b); }
__device__ __forceinline__ h2 pmin(h2 a, h2 b) { return __builtin_elementwise_min(a, b); }
__device__ __forceinline__ _Float16 smax(_Float16 a, _Float16 b) {
  return __builtin_elementwise_max(a, b);
}
__device__ __forceinline__ _Float16 smin(_Float16 a, _Float16 b) {
  return __builtin_elementwise_min(a, b);
}

// packed bitonic apply
#define DEF_PK(NAME, NET, L)                                        \
  __device__ __forceinline__ void NAME(h2(&v)[L]) {                 \
    _Pragma("unroll") for (int c = 0; c < NET.npk; ++c) {           \
      h2 a = v[NET.pa[c]], b = v[NET.pb[c]];                        \
      v[NET.pa[c]] = pmax(a, b);                                    \
      v[NET.pb[c]] = pmin(a, b);                                    \
    }                                                               \
    _Pragma("unroll") for (int c = 0; c < NET.nsc; ++c) {           \
      const int j = NET.sc[c];                                      \
      _Float16 a = v[j].x, b = v[j].y;                              \
      v[j].x = smax(a, b);                                          \
      v[j].y = smin(a, b);                                          \
    }                                                               \
  }

DEF_PK(pk16, PK16, 8)
DEF_PK(pk32, PK32, 16)
DEF_PK(pk36, PK36, 18)

// column-packed (L in .x, R in .y) scalar-net apply: every CE is one pk pair
#define DEF_COL(NAME, NET, L)                                       \
  __device__ __forceinline__ void NAME(h2(&v)[L]) {                 \
    _Pragma("unroll") for (int c = 0; c < NET.cnt; ++c) {           \
      h2 a = v[NET.a[c]], b = v[NET.b[c]];                          \
      v[NET.a[c]] = pmax(a, b);                                     \
      v[NET.b[c]] = pmin(a, b);                                     \
    }                                                               \
  }

DEF_COL(col8, NET8, 8)
DEF_COL(col5, NET5, 5)
DEF_COL(col13, B13, 13)

// merged-26 element access for the stage b26 (e<13 -> Lf[e]=f[e].x,
// e>=13 -> Rf[25-e]=f[25-e].y); indices constant after unroll.
__device__ __forceinline__ void b26_scalar(h2 (&f)[13]) {
#pragma unroll
  for (int c = 0; c < B26S.cnt; ++c) {
    const int A = B26S.a[c], B = B26S.b[c];
    _Float16 x = (A < 13) ? f[A].x : f[25 - A].y;
    _Float16 y = (B < 13) ? f[B].x : f[25 - B].y;
    _Float16 mx = smax(x, y), mn = smin(x, y);
    if (A < 13) f[A].x = mx; else f[25 - A].y = mx;
    if (B < 13) f[B].x = mn; else f[25 - B].y = mn;
  }
}

// pair-list (28 halfs as 7 h4) element-pair extract: pr = (e2j, e2j+1)
__device__ __forceinline__ h2 pr(const h4 (&r)[7], int j) {
  return mk2(r[j >> 1][2 * (j & 1)], r[j >> 1][2 * (j & 1) + 1]);
}
__device__ __forceinline__ h2 prs(const h4 (&r)[7], int j) {
  return mk2(r[j >> 1][2 * (j & 1) + 1], r[j >> 1][2 * (j & 1)]);
}
// gap-col (h8) pair extract
__device__ __forceinline__ h2 g2c(h8 v, int j) { return mk2(v[2 * j], v[2 * j + 1]); }
__device__ __forceinline__ h2 g2cs(h8 v, int j) { return mk2(v[2 * j + 1], v[2 * j]); }

__device__ __forceinline__ void load26(const _Float16* row, h4 (&r)[7]) {
  const h4* p = (const h4*)row;
#pragma unroll
  for (int k = 0; k < 7; ++k) r[k] = p[k];
}

// top-36 multiset of two descending sorted-26 lists -> bitonic-36 in S
__device__ __forceinline__ void cap36(h2 (&S)[18], const h4 (&x)[7], const h4 (&y)[7]) {
#pragma unroll
  for (int j = 0; j < 5; ++j) S[j] = pr(x, j);
#pragma unroll
  for (int j = 5; j < 13; ++j) S[j] = pmax(pr(x, j), prs(y, 17 - j));
#pragma unroll
  for (int j = 13; j < 18; ++j) S[j] = prs(y, 17 - j);
}

__global__ __launch_bounds__(256, 8) void cfar_os_kernel(const float* __restrict__ in,
                                                         float* __restrict__ out,
                                                         float alpha) {
  __shared__ __attribute__((aligned(16))) _Float16 smem[COLS * SG_W + NPAIR * SP_W];
  _Float16* sg = smem;                 // [268][8]  sorted gap-8 (left col), 16B rows
  _Float16* sp = smem + COLS * SG_W;   // [267][28] sorted-26 pairs, 56B rows

  const int t = threadIdx.x;
  const int r0 = blockIdx.y;
  const int c0 = blockIdx.x * TX;

  // ---- cooperative stage: column-pair tasks, both columns packed in .x/.y ----
  for (int cc = t; cc < NPAIR; cc += 256) {
    const int gl = (c0 + cc - 6) & (RDIM - 1);
    const int gr = (gl + 1) & (RDIM - 1);
    h2 c[13];
#pragma unroll
    for (int dy = 0; dy < 13; ++dy) {
      const int rb = ((r0 + dy - 6) & (VDIM - 1)) << 10;
      c[dy] = mk2((_Float16)in[rb + gl], (_Float16)in[rb + gr]);
    }
    h2 g[8] = {c[0], c[1], c[2], c[3], c[9], c[10], c[11], c[12]};
    col8(g);
    h2 m[5] = {c[4], c[5], c[6], c[7], c[8]};
    col5(m);
    h2 f[13];
#pragma unroll
    for (int p = 0; p < 8; ++p) f[p] = g[p];
    f[8] = m[4]; f[9] = m[3]; f[10] = m[2]; f[11] = m[1]; f[12] = m[0];
    col13(f);       // sorted-13 desc for BOTH cols
    b26_scalar(f);  // merge L desc + R asc -> sorted-26 desc (in .x/.y halves)

    // pack sorted-26 into contiguous halfs (+2 pad) and store (7 x b64)
    _Float16* row = sp + cc * SP_W;
    h4 w0 = {f[0].x, f[1].x, f[2].x, f[3].x};
    h4 w1 = {f[4].x, f[5].x, f[6].x, f[7].x};
    h4 w2 = {f[8].x, f[9].x, f[10].x, f[11].x};
    h4 w3 = {f[12].x, f[12].y, f[11].y, f[10].y};
    h4 w4 = {f[9].y, f[8].y, f[7].y, f[6].y};
    h4 w5 = {f[5].y, f[4].y, f[3].y, f[2].y};
    h4 w6 = {f[1].y, f[0].y, NINF, NINF};
    h4* pw = (h4*)row;
    pw[0] = w0; pw[1] = w1; pw[2] = w2; pw[3] = w3; pw[4] = w4; pw[5] = w5; pw[6] = w6;

    // left col's sorted gap-8
    h4 ga = {g[0].x, g[1].x, g[2].x, g[3].x};
    h4 gb = {g[4].x, g[5].x, g[6].x, g[7].x};
    h4* pg = (h4*)(sg + cc * SG_W);
    pg[0] = ga; pg[1] = gb;
  }
  __syncthreads();

  // ---- per-pixel phase ----
  h4 xr[7], yr[7];
  load26(sp + (t + 9) * SP_W, xr);
  load26(sp + (t + 11) * SP_W, yr);
  h2 B[18];
  cap36(B, xr, yr);

  // issue gap-col loads, then sort B while they are in flight
  h8 gc0 = *(const h8*)(sg + (t + 4) * SG_W);
  h8 gc1 = *(const h8*)(sg + (t + 5) * SG_W);
  h8 gc2 = *(const h8*)(sg + (t + 6) * SG_W);
  h8 gc3 = *(const h8*)(sg + (t + 7) * SG_W);
  h8 gc4 = *(const h8*)(sg + (t + 8) * SG_W);
  pk36(B);

  // gap pairs -> sorted-16 each -> sorted-32
  h2 g1[8] = {g2c(gc0, 0), g2c(gc0, 1), g2c(gc0, 2), g2c(gc0, 3),
              g2cs(gc1, 3), g2cs(gc1, 2), g2cs(gc1, 1), g2cs(gc1, 0)};
  pk16(g1);
  h2 g2[8] = {g2c(gc2, 0), g2c(gc2, 1), g2c(gc2, 2), g2c(gc2, 3),
              g2cs(gc3, 3), g2cs(gc3, 2), g2cs(gc3, 1), g2cs(gc3, 0)};
  pk16(g2);
  h2 G[16];
#pragma unroll
  for (int j = 0; j < 8; ++j) G[j] = g1[j];
#pragma unroll
  for (int j = 8; j < 16; ++j) G[j] = g2[15 - j].yx;
  pk32(G);

  // fold sorted-32 into B (i>=4 real; j=0,1 hit pads only)
#pragma unroll
  for (int j = 2; j < 18; ++j) B[j] = pmax(B[j], G[17 - j].yx);

  // issue A-side loads before the next sort chains
  load26(sp + (t + 0) * SP_W, xr);
  load26(sp + (t + 2) * SP_W, yr);

  pk36(B);
  // fold last gap col (sorted-8)
  B[14] = pmax(B[14], g2cs(gc4, 3));
  B[15] = pmax(B[15], g2cs(gc4, 2));
  B[16] = pmax(B[16], g2cs(gc4, 1));
  B[17] = pmax(B[17], g2cs(gc4, 0));
  pk36(B);

  h2 A[18];
  cap36(A, xr, yr);
  pk36(A);

  // ---- final: 36th largest of union = min_i max(A_i, B_{35-i}) ----
  h2 r = pmax(A[0], B[17].yx);
#pragma unroll
  for (int j = 1; j < 18; ++j) r = pmin(r, pmax(A[j], B[17 - j].yx));
  _Float16 m = smin(r.x, r.y);

  out[(r0 << 10) + c0 + t] = alpha * (float)m;
}

// ---- host-side faithful port of the reference ALPHA computation ----
static double log_factorial_port(int n_) {
  double n = n_ + 1.0;
  if (n < 9.0) {
    double f = 1.0;
    for (int i = 2; i <= (int)(n + 0.5); ++i) f *= (double)i;
    return log(f);
  }
  return 0.5 * (log(2.0 * M_PI) - log(n)) +
         n * (log(n + 1.0 / (12.0 * n - 1.0 / (10.0 * n))) - 1.0);
}

static double cfar_fun(int k, int n, double t, double pfa) {
  double s = 0.0;
  for (int i = n; i > n - k; --i) s += log((double)i + t);
  return log_factorial_port(n) - log_factorial_port(n - k) - s - log(pfa);
}

static float compute_alpha() {
  double lo = 1.0, hi = 1e32;
  for (int it = 0; it < 300; ++it) {
    double mid = 0.5 * (lo + hi);
    if (cfar_fun(108, 144, mid, 1e-5) > 0.0)
      lo = mid;
    else
      hi = mid;
  }
  return (float)(0.5 * (lo + hi));
}

static const float g_alpha = compute_alpha();

extern "C" void kernel_launch(void* const* d_in, const int* in_sizes, int n_in,
                              void* d_out, int out_size, void* d_ws, size_t ws_size,
                              hipStream_t stream) {
  const float* in = (const float*)d_in[0];
  float* out = (float*)d_out;
  dim3 block(TX, 1);
  dim3 grid(RDIM / TX, VDIM);
  hipLaunchKernelGGL(cfar_os_kernel, grid, block, 0, stream, in, out, g_alpha);
}

// Round 7
// 20.006 us; speedup vs baseline: 1.7465x; 1.1778x over previous
//
#include <hip/hip_runtime.h>
#include <cmath>

#ifndef M_PI
#define M_PI 3.14159265358979323846
#endif

typedef _Float16 h2 __attribute__((ext_vector_type(2)));

namespace {

constexpr int VDIM = 512;
constexpr int RDIM = 1024;
constexpr int TX = 256;          // pixel columns per block
constexpr int COLS = TX + 12;    // 268 cols incl. halo
constexpr int NPAIR = COLS - 1;  // 267 adjacent-col pairs

constexpr int SP_W = 28;  // h2 per pair row (112 B, 16B-aligned)
constexpr int SG_W = 8;   // h2 per gap row (32 B)

struct Net {
  int cnt;
  int a[96];
  int b[96];
};

// Batcher odd-even mergesort (arbitrary n), descending (max to low index).
constexpr Net make_batcher(int n) {
  Net net{};
  net.cnt = 0;
  for (int p = 1; p < n; p *= 2)
    for (int k = p; k >= 1; k /= 2)
      for (int j = k % p; j + k < n; j += 2 * k)
        for (int i = 0; i < k && i + j + k < n; ++i)
          if ((i + j) / (2 * p) == (i + j + k) / (2 * p)) {
            net.a[net.cnt] = i + j;
            net.b[net.cnt] = i + j + k;
            ++net.cnt;
          }
  return net;
}

// Descending sorter for a BITONIC input of length n (front +inf pads elided).
constexpr Net make_bitonic_desc(int n) {
  int P = 1;
  while (P < n) P *= 2;
  int F = P - n;
  Net net{};
  net.cnt = 0;
  for (int d = P / 2; d >= 1; d /= 2)
    for (int i = F; i + d < P; ++i)
      if ((i & d) == 0) {
        net.a[net.cnt] = i - F;
        net.b[net.cnt] = i - F + d;
        ++net.cnt;
      }
  return net;
}

constexpr Net NET8 = make_batcher(8);
constexpr Net NET5 = make_batcher(5);
constexpr Net B13 = make_bitonic_desc(13);
constexpr Net B16 = make_bitonic_desc(16);
constexpr Net B26 = make_bitonic_desc(26);
constexpr Net B32 = make_bitonic_desc(32);
constexpr Net B36 = make_bitonic_desc(36);

}  // namespace

__device__ __forceinline__ h2 mk2(_Float16 a, _Float16 b) {
  h2 v;
  v.x = a;
  v.y = b;
  return v;
}
__device__ __forceinline__ h2 pmax(h2 a, h2 b) { return __builtin_elementwise_max(a, b); }
__device__ __forceinline__ h2 pmin(h2 a, h2 b) { return __builtin_elementwise_min(a, b); }
__device__ __forceinline__ h2 bch(float f) { return __builtin_bit_cast(h2, f); }
__device__ __forceinline__ float bcf(h2 h) { return __builtin_bit_cast(float, h); }

// every comparator fully packed: rows (r0, r0+1) ride in .x/.y
#define DEF_NET(NAME, NET, L)                                       \
  __device__ __forceinline__ void NAME(h2(&v)[L]) {                 \
    _Pragma("unroll") for (int c = 0; c < NET.cnt; ++c) {           \
      h2 a = v[NET.a[c]], b = v[NET.b[c]];                          \
      v[NET.a[c]] = pmax(a, b);                                     \
      v[NET.b[c]] = pmin(a, b);                                     \
    }                                                               \
  }

DEF_NET(net8p, NET8, 8)
DEF_NET(net5p, NET5, 5)
DEF_NET(b13p, B13, 13)
DEF_NET(b16p, B16, 16)
DEF_NET(b26p, B26, 26)
DEF_NET(b32p, B32, 32)
DEF_NET(b36p, B36, 36)

// one column, both rows packed: f = sorted-13 desc, g = sorted gap-8 desc
__device__ __forceinline__ void col_chain(const h2 (&c)[13], h2 (&f)[13], h2 (&g)[8]) {
  g[0] = c[0]; g[1] = c[1]; g[2] = c[2]; g[3] = c[3];
  g[4] = c[9]; g[5] = c[10]; g[6] = c[11]; g[7] = c[12];
  net8p(g);
  h2 m[5] = {c[4], c[5], c[6], c[7], c[8]};
  net5p(m);
#pragma unroll
  for (int p = 0; p < 8; ++p) f[p] = g[p];
  f[8] = m[4]; f[9] = m[3]; f[10] = m[2]; f[11] = m[1]; f[12] = m[0];
  b13p(f);
}

__device__ __forceinline__ void ld26(const h2* row, h2 (&d)[26]) {
#pragma unroll
  for (int k = 0; k < 6; ++k) {
    float4 w = *(const float4*)(row + 4 * k);
    d[4 * k + 0] = bch(w.x); d[4 * k + 1] = bch(w.y);
    d[4 * k + 2] = bch(w.z); d[4 * k + 3] = bch(w.w);
  }
  float2 w = *(const float2*)(row + 24);
  d[24] = bch(w.x); d[25] = bch(w.y);
}

__device__ __forceinline__ void ld8(const h2* row, h2 (&d)[8]) {
  float4 a = *(const float4*)(row);
  float4 b = *(const float4*)(row + 4);
  d[0] = bch(a.x); d[1] = bch(a.y); d[2] = bch(a.z); d[3] = bch(a.w);
  d[4] = bch(b.x); d[5] = bch(b.y); d[6] = bch(b.z); d[7] = bch(b.w);
}

// top-36 multiset of two descending sorted-26 lists -> bitonic-36
__device__ __forceinline__ void cap36(h2 (&S)[36], const h2 (&x)[26], const h2 (&y)[26]) {
#pragma unroll
  for (int i = 0; i < 10; ++i) S[i] = x[i];
#pragma unroll
  for (int i = 10; i < 26; ++i) S[i] = pmax(x[i], y[35 - i]);
#pragma unroll
  for (int i = 26; i < 36; ++i) S[i] = y[35 - i];
}

__global__ __launch_bounds__(256, 4) void cfar_os_kernel(const float* __restrict__ in,
                                                         float* __restrict__ out,
                                                         float alpha) {
  __shared__ __attribute__((aligned(16))) h2 smem[NPAIR * SP_W + COLS * SG_W];
  h2* SP = smem;                    // [267][28] sorted-26 pairs (both rows packed)
  h2* SG = smem + NPAIR * SP_W;     // [268][8]  sorted gap-8 (left col)

  const int t = threadIdx.x;
  const int r0 = blockIdx.y * 2;    // row pair (r0 in .x, r0+1 in .y)
  const int c0 = blockIdx.x * TX;

  // ---- cooperative stage: col-pair task, 2 cols x 2 rows per task ----
  for (int cc = t; cc < NPAIR; cc += 256) {
    const int gl = (c0 + cc - 6) & (RDIM - 1);
    const int gr = (gl + 1) & (RDIM - 1);
    float rwx[14], rwy[14];
#pragma unroll
    for (int dy = 0; dy < 14; ++dy) {
      const int rb = ((r0 + dy - 6) & (VDIM - 1)) << 10;
      rwx[dy] = in[rb + gl];
      rwy[dy] = in[rb + gr];
    }
    h2 cL[13], cR[13];
#pragma unroll
    for (int dy = 0; dy < 13; ++dy) {
      cL[dy] = mk2((_Float16)rwx[dy], (_Float16)rwx[dy + 1]);
      cR[dy] = mk2((_Float16)rwy[dy], (_Float16)rwy[dy + 1]);
    }
    h2 fL[13], gL[8], fR[13], gR[8];
    col_chain(cL, fL, gL);
    col_chain(cR, fR, gR);
    h2 v[26];
#pragma unroll
    for (int j = 0; j < 13; ++j) v[j] = fL[j];
#pragma unroll
    for (int j = 0; j < 13; ++j) v[13 + j] = fR[12 - j];
    b26p(v);  // sorted-26 desc, both rows

    h2* row = SP + cc * SP_W;
#pragma unroll
    for (int k = 0; k < 6; ++k)
      *(float4*)(row + 4 * k) = make_float4(bcf(v[4 * k]), bcf(v[4 * k + 1]),
                                            bcf(v[4 * k + 2]), bcf(v[4 * k + 3]));
    *(float2*)(row + 24) = make_float2(bcf(v[24]), bcf(v[25]));

    h2* grow = SG + cc * SG_W;
    *(float4*)(grow) = make_float4(bcf(gL[0]), bcf(gL[1]), bcf(gL[2]), bcf(gL[3]));
    *(float4*)(grow + 4) = make_float4(bcf(gL[4]), bcf(gL[5]), bcf(gL[6]), bcf(gL[7]));
  }
  __syncthreads();

  // ---- per-pixel-pair phase (all comparators packed) ----
  // Y = sorted top-36 of the 5 gap columns (40 cells)
  h2 Y[36];
  {
    h2 gc0[8], gc1[8], gc2[8], gc3[8], gc4[8];
    ld8(SG + (t + 4) * SG_W, gc0);
    ld8(SG + (t + 5) * SG_W, gc1);
    ld8(SG + (t + 6) * SG_W, gc2);
    ld8(SG + (t + 7) * SG_W, gc3);
    ld8(SG + (t + 8) * SG_W, gc4);
    h2 g1[16], g2[16];
#pragma unroll
    for (int j = 0; j < 8; ++j) { g1[j] = gc0[j]; g1[8 + j] = gc1[7 - j]; }
    b16p(g1);
#pragma unroll
    for (int j = 0; j < 8; ++j) { g2[j] = gc2[j]; g2[8 + j] = gc3[7 - j]; }
    b16p(g2);
    h2 G[32];
#pragma unroll
    for (int j = 0; j < 16; ++j) { G[j] = g1[j]; G[16 + j] = g2[15 - j]; }
    b32p(G);
#pragma unroll
    for (int i = 0; i < 28; ++i) Y[i] = G[i];
#pragma unroll
    for (int i = 28; i < 32; ++i) Y[i] = pmax(G[i], gc4[35 - i]);
#pragma unroll
    for (int i = 32; i < 36; ++i) Y[i] = gc4[35 - i];
    b36p(Y);
  }

  // Z = sorted top-36 of B-side full cols (t+3..t+6 rel) folded with Y
  h2 Z[36];
  {
    h2 x[26], y[26];
    ld26(SP + (t + 9) * SP_W, x);
    ld26(SP + (t + 11) * SP_W, y);
    h2 B[36];
    cap36(B, x, y);
    b36p(B);
#pragma unroll
    for (int i = 0; i < 36; ++i) Z[i] = pmax(B[i], Y[35 - i]);
    b36p(Z);
  }

  // A = sorted top-36 of A-side full cols (t-6..t-3 rel)
  h2 A[36];
  {
    h2 x[26], y[26];
    ld26(SP + (t + 0) * SP_W, x);
    ld26(SP + (t + 2) * SP_W, y);
    cap36(A, x, y);
    b36p(A);
  }

  // final: 36th largest of union = min_i max(A_i, Z_{35-i})
  h2 mm[36];
#pragma unroll
  for (int i = 0; i < 36; ++i) mm[i] = pmax(A[i], Z[35 - i]);
#pragma unroll
  for (int i = 0; i < 18; ++i) mm[i] = pmin(mm[i], mm[i + 18]);
#pragma unroll
  for (int i = 0; i < 9; ++i) mm[i] = pmin(mm[i], mm[i + 9]);
#pragma unroll
  for (int i = 0; i < 4; ++i) mm[i] = pmin(mm[i], mm[i + 4]);
  mm[0] = pmin(mm[0], mm[8]);
  mm[0] = pmin(mm[0], pmin(mm[1], pmin(mm[2], mm[3])));

  const int oc = c0 + t;
  out[(r0 << 10) + oc] = alpha * (float)mm[0].x;
  out[((r0 + 1) << 10) + oc] = alpha * (float)mm[0].y;
}

// ---- host-side faithful port of the reference ALPHA computation ----
static double log_factorial_port(int n_) {
  double n = n_ + 1.0;
  if (n < 9.0) {
    double f = 1.0;
    for (int i = 2; i <= (int)(n + 0.5); ++i) f *= (double)i;
    return log(f);
  }
  return 0.5 * (log(2.0 * M_PI) - log(n)) +
         n * (log(n + 1.0 / (12.0 * n - 1.0 / (10.0 * n))) - 1.0);
}

static double cfar_fun(int k, int n, double t, double pfa) {
  double s = 0.0;
  for (int i = n; i > n - k; --i) s += log((double)i + t);
  return log_factorial_port(n) - log_factorial_port(n - k) - s - log(pfa);
}

static float compute_alpha() {
  double lo = 1.0, hi = 1e32;
  for (int it = 0; it < 300; ++it) {
    double mid = 0.5 * (lo + hi);
    if (cfar_fun(108, 144, mid, 1e-5) > 0.0)
      lo = mid;
    else
      hi = mid;
  }
  return (float)(0.5 * (lo + hi));
}

static const float g_alpha = compute_alpha();

extern "C" void kernel_launch(void* const* d_in, const int* in_sizes, int n_in,
                              void* d_out, int out_size, void* d_ws, size_t ws_size,
                              hipStream_t stream) {
  const float* in = (const float*)d_in[0];
  float* out = (float*)d_out;
  dim3 block(TX, 1);
  dim3 grid(RDIM / TX, VDIM / 2);
  hipLaunchKernelGGL(cfar_os_kernel, grid, block, 0, stream, in, out, g_alpha);
}

// Round 8
// 19.442 us; speedup vs baseline: 1.7972x; 1.0290x over previous
//
#include <hip/hip_runtime.h>
#include <cmath>

#ifndef M_PI
#define M_PI 3.14159265358979323846
#endif

typedef _Float16 h2 __attribute__((ext_vector_type(2)));

namespace {

constexpr int VDIM = 512;
constexpr int RDIM = 1024;
constexpr int TX = 256;          // pixel columns per block
constexpr int COLS = TX + 12;    // 268 cols incl. halo
constexpr int NPAIR = COLS - 1;  // 267 adjacent-col pairs

constexpr int SP_W = 28;  // h2 per pair row (112 B, 16B-aligned)

struct Net {
  int cnt;
  int a[96];
  int b[96];
};

// Batcher odd-even mergesort (arbitrary n), descending (max to low index).
constexpr Net make_batcher(int n) {
  Net net{};
  net.cnt = 0;
  for (int p = 1; p < n; p *= 2)
    for (int k = p; k >= 1; k /= 2)
      for (int j = k % p; j + k < n; j += 2 * k)
        for (int i = 0; i < k && i + j + k < n; ++i)
          if ((i + j) / (2 * p) == (i + j + k) / (2 * p)) {
            net.a[net.cnt] = i + j;
            net.b[net.cnt] = i + j + k;
            ++net.cnt;
          }
  return net;
}

// Descending sorter for a BITONIC input of length n (front +inf pads elided).
constexpr Net make_bitonic_desc(int n) {
  int P = 1;
  while (P < n) P *= 2;
  int F = P - n;
  Net net{};
  net.cnt = 0;
  for (int d = P / 2; d >= 1; d /= 2)
    for (int i = F; i + d < P; ++i)
      if ((i & d) == 0) {
        net.a[net.cnt] = i - F;
        net.b[net.cnt] = i - F + d;
        ++net.cnt;
      }
  return net;
}

constexpr Net NET8 = make_batcher(8);
constexpr Net NET5 = make_batcher(5);
constexpr Net B13 = make_bitonic_desc(13);
constexpr Net B16 = make_bitonic_desc(16);
constexpr Net B26 = make_bitonic_desc(26);
constexpr Net B32 = make_bitonic_desc(32);
constexpr Net B36 = make_bitonic_desc(36);

}  // namespace

__device__ __forceinline__ h2 mk2(_Float16 a, _Float16 b) {
  h2 v;
  v.x = a;
  v.y = b;
  return v;
}
__device__ __forceinline__ h2 pmax(h2 a, h2 b) { return __builtin_elementwise_max(a, b); }
__device__ __forceinline__ h2 pmin(h2 a, h2 b) { return __builtin_elementwise_min(a, b); }
__device__ __forceinline__ h2 bch(float f) { return __builtin_bit_cast(h2, f); }
__device__ __forceinline__ float bcf(h2 h) { return __builtin_bit_cast(float, h); }

// every comparator fully packed: rows (r0, r0+1) ride in .x/.y
#define DEF_NET(NAME, NET, L)                                       \
  __device__ __forceinline__ void NAME(h2(&v)[L]) {                 \
    _Pragma("unroll") for (int c = 0; c < NET.cnt; ++c) {           \
      h2 a = v[NET.a[c]], b = v[NET.b[c]];                          \
      v[NET.a[c]] = pmax(a, b);                                     \
      v[NET.b[c]] = pmin(a, b);                                     \
    }                                                               \
  }

DEF_NET(net8p, NET8, 8)
DEF_NET(net5p, NET5, 5)
DEF_NET(b13p, B13, 13)
DEF_NET(b16p, B16, 16)
DEF_NET(b26p, B26, 26)
DEF_NET(b32p, B32, 32)
DEF_NET(b36p, B36, 36)

// one column, both rows packed: f = sorted-13 desc, g = sorted gap-8 desc
__device__ __forceinline__ void col_chain(const h2 (&c)[13], h2 (&f)[13], h2 (&g)[8]) {
  g[0] = c[0]; g[1] = c[1]; g[2] = c[2]; g[3] = c[3];
  g[4] = c[9]; g[5] = c[10]; g[6] = c[11]; g[7] = c[12];
  net8p(g);
  h2 m[5] = {c[4], c[5], c[6], c[7], c[8]};
  net5p(m);
#pragma unroll
  for (int p = 0; p < 8; ++p) f[p] = g[p];
  f[8] = m[4]; f[9] = m[3]; f[10] = m[2]; f[11] = m[1]; f[12] = m[0];
  b13p(f);
}

__device__ __forceinline__ void ld26(const h2* row, h2 (&d)[26]) {
#pragma unroll
  for (int k = 0; k < 6; ++k) {
    float4 w = *(const float4*)(row + 4 * k);
    d[4 * k + 0] = bch(w.x); d[4 * k + 1] = bch(w.y);
    d[4 * k + 2] = bch(w.z); d[4 * k + 3] = bch(w.w);
  }
  float2 w = *(const float2*)(row + 24);
  d[24] = bch(w.x); d[25] = bch(w.y);
}

// gap-8 col from the split 16B-row arrays (2-way banks = free)
__device__ __forceinline__ void ldg8(const h2* SGa, const h2* SGb, int c, h2 (&d)[8]) {
  float4 a = *(const float4*)(SGa + 4 * c);
  float4 b = *(const float4*)(SGb + 4 * c);
  d[0] = bch(a.x); d[1] = bch(a.y); d[2] = bch(a.z); d[3] = bch(a.w);
  d[4] = bch(b.x); d[5] = bch(b.y); d[6] = bch(b.z); d[7] = bch(b.w);
}

// top-36 multiset of two descending sorted-26 lists -> bitonic-36
__device__ __forceinline__ void cap36(h2 (&S)[36], const h2 (&x)[26], const h2 (&y)[26]) {
#pragma unroll
  for (int i = 0; i < 10; ++i) S[i] = x[i];
#pragma unroll
  for (int i = 10; i < 26; ++i) S[i] = pmax(x[i], y[35 - i]);
#pragma unroll
  for (int i = 26; i < 36; ++i) S[i] = y[35 - i];
}

__global__ __launch_bounds__(256, 4) void cfar_os_kernel(const float* __restrict__ in,
                                                         float* __restrict__ out,
                                                         float alpha) {
  __shared__ __attribute__((aligned(16))) h2 SP[NPAIR * SP_W];  // sorted-26 pairs
  __shared__ __attribute__((aligned(16))) h2 SGa[COLS * 4];     // gap-8 lo half
  __shared__ __attribute__((aligned(16))) h2 SGb[COLS * 4];     // gap-8 hi half

  const int t = threadIdx.x;
  const int r0 = blockIdx.y * 2;  // row pair (r0 in .x, r0+1 in .y)
  const int c0 = blockIdx.x * TX;

  // ---- cooperative stage: col-pair task, 2 cols x 2 rows per task ----
  for (int cc = t; cc < NPAIR; cc += 256) {
    const int gl = (c0 + cc - 6) & (RDIM - 1);
    const int gr = (gl + 1) & (RDIM - 1);
    float rwx[14], rwy[14];
#pragma unroll
    for (int dy = 0; dy < 14; ++dy) {
      const int rb = ((r0 + dy - 6) & (VDIM - 1)) << 10;
      rwx[dy] = in[rb + gl];
      rwy[dy] = in[rb + gr];
    }
    h2 cL[13], cR[13];
#pragma unroll
    for (int dy = 0; dy < 13; ++dy) {
      cL[dy] = mk2((_Float16)rwx[dy], (_Float16)rwx[dy + 1]);
      cR[dy] = mk2((_Float16)rwy[dy], (_Float16)rwy[dy + 1]);
    }
    h2 fL[13], gL[8], fR[13], gR[8];
    col_chain(cL, fL, gL);
    col_chain(cR, fR, gR);
    h2 v[26];
#pragma unroll
    for (int j = 0; j < 13; ++j) v[j] = fL[j];
#pragma unroll
    for (int j = 0; j < 13; ++j) v[13 + j] = fR[12 - j];
    b26p(v);  // sorted-26 desc, both rows

    h2* row = SP + cc * SP_W;
#pragma unroll
    for (int k = 0; k < 6; ++k)
      *(float4*)(row + 4 * k) = make_float4(bcf(v[4 * k]), bcf(v[4 * k + 1]),
                                            bcf(v[4 * k + 2]), bcf(v[4 * k + 3]));
    *(float2*)(row + 24) = make_float2(bcf(v[24]), bcf(v[25]));

    *(float4*)(SGa + 4 * cc) = make_float4(bcf(gL[0]), bcf(gL[1]), bcf(gL[2]), bcf(gL[3]));
    *(float4*)(SGb + 4 * cc) = make_float4(bcf(gL[4]), bcf(gL[5]), bcf(gL[6]), bcf(gL[7]));
  }
  __syncthreads();

  // ---- per-pixel-pair phase: single running sorted top-36 accumulator ----
  h2 S[36];
  {  // B-side full cols (abs dx +3..+6)
    h2 x[26], y[26];
    ld26(SP + (t + 9) * SP_W, x);
    ld26(SP + (t + 11) * SP_W, y);
    cap36(S, x, y);
  }
  // issue gap loads before the sort chain
  h2 gc0[8], gc1[8], gc2[8], gc3[8];
  ldg8(SGa, SGb, t + 4, gc0);
  ldg8(SGa, SGb, t + 5, gc1);
  ldg8(SGa, SGb, t + 6, gc2);
  ldg8(SGa, SGb, t + 7, gc3);
  b36p(S);  // #1

  {  // gap merge tree: 4 cols -> sorted-32, fold into S
    h2 g1[16], g2[16];
#pragma unroll
    for (int j = 0; j < 8; ++j) { g1[j] = gc0[j]; g1[8 + j] = gc1[7 - j]; }
    b16p(g1);
#pragma unroll
    for (int j = 0; j < 8; ++j) { g2[j] = gc2[j]; g2[8 + j] = gc3[7 - j]; }
    b16p(g2);
    h2 G[32];
#pragma unroll
    for (int j = 0; j < 16; ++j) { G[j] = g1[j]; G[16 + j] = g2[15 - j]; }
    b32p(G);
#pragma unroll
    for (int i = 4; i < 36; ++i) S[i] = pmax(S[i], G[35 - i]);
  }
  h2 gc4[8];
  ldg8(SGa, SGb, t + 8, gc4);
  b36p(S);  // #2

#pragma unroll
  for (int i = 28; i < 36; ++i) S[i] = pmax(S[i], gc4[35 - i]);
  h2 x1[26];
  ld26(SP + (t + 0) * SP_W, x1);  // A-pair 1 (abs dx -6,-5)
  b36p(S);  // #3

#pragma unroll
  for (int i = 10; i < 36; ++i) S[i] = pmax(S[i], x1[35 - i]);
  h2 q[26];
  ld26(SP + (t + 2) * SP_W, q);  // A-pair 2 (abs dx -4,-3)
  b36p(S);  // #4

  // final rank identity with the last sorted-26 chunk:
  // ans = min(S_9, min_{i=10..35} max(S_i, q_{35-i}))
  h2 r = S[9];
#pragma unroll
  for (int i = 10; i < 36; ++i) r = pmin(r, pmax(S[i], q[35 - i]));

  const int oc = c0 + t;
  out[(r0 << 10) + oc] = alpha * (float)r.x;
  out[((r0 + 1) << 10) + oc] = alpha * (float)r.y;
}

// ---- host-side faithful port of the reference ALPHA computation ----
static double log_factorial_port(int n_) {
  double n = n_ + 1.0;
  if (n < 9.0) {
    double f = 1.0;
    for (int i = 2; i <= (int)(n + 0.5); ++i) f *= (double)i;
    return log(f);
  }
  return 0.5 * (log(2.0 * M_PI) - log(n)) +
         n * (log(n + 1.0 / (12.0 * n - 1.0 / (10.0 * n))) - 1.0);
}

static double cfar_fun(int k, int n, double t, double pfa) {
  double s = 0.0;
  for (int i = n; i > n - k; --i) s += log((double)i + t);
  return log_factorial_port(n) - log_factorial_port(n - k) - s - log(pfa);
}

static float compute_alpha() {
  double lo = 1.0, hi = 1e32;
  for (int it = 0; it < 300; ++it) {
    double mid = 0.5 * (lo + hi);
    if (cfar_fun(108, 144, mid, 1e-5) > 0.0)
      lo = mid;
    else
      hi = mid;
  }
  return (float)(0.5 * (lo + hi));
}

static const float g_alpha = compute_alpha();

extern "C" void kernel_launch(void* const* d_in, const int* in_sizes, int n_in,
                              void* d_out, int out_size, void* d_ws, size_t ws_size,
                              hipStream_t stream) {
  const float* in = (const float*)d_in[0];
  float* out = (float*)d_out;
  dim3 block(TX, 1);
  dim3 grid(RDIM / TX, VDIM / 2);
  hipLaunchKernelGGL(cfar_os_kernel, grid, block, 0, stream, in, out, g_alpha);
}